// Round 5
// baseline (49.641 us; speedup 1.0000x reference)
//
#include <hip/hip_runtime.h>

// MVDR beamformer pipeline: STFT -> causal PSD (in-register scan) -> Souden MVDR -> beamform -> iSTFT
static constexpr int NFFT = 4096;
static constexpr int HOP  = 1024;
static constexpr int NF   = 2049;   // rfft bins
static constexpr int NT   = 29;     // frames
static constexpr int NS   = 32768;  // samples per channel
static constexpr int NB   = 2;      // batch
static constexpr int NSrc = 2;      // sources
static constexpr int NC   = 4;      // channels
static constexpr int NBS  = NB * NSrc;
static constexpr int FCHUNKS = (NF + 7) / 8;  // 257 f-chunks of 8 per block

#define PI_F     3.14159265358979323846f
#define TWO_PI_F 6.28318530717958647692f

// LDS padding: one extra float every 16 -> breaks all power-of-2 stride conflicts
#define IDX(a) ((a) + ((a) >> 4))
static constexpr int LDSN = 2048 + 128;  // padded length

__device__ inline float2 cmul(float2 a, float2 b) {
    return make_float2(a.x * b.x - a.y * b.y, a.x * b.y + a.y * b.x);
}
// a * conj(b)
__device__ inline float2 cmulc(float2 a, float2 b) {
    return make_float2(a.x * b.x + a.y * b.y, a.y * b.x - a.x * b.y);
}

// ---------------------------------------------------------------------------
// 4- and 8-point DFT building blocks. DIR=-1 forward (e^{-i}), +1 inverse.
// ---------------------------------------------------------------------------
template <int DIR>
__device__ inline void fft4v(float2 v[4]) {
    float2 t0 = make_float2(v[0].x + v[2].x, v[0].y + v[2].y);
    float2 t1 = make_float2(v[0].x - v[2].x, v[0].y - v[2].y);
    float2 t2 = make_float2(v[1].x + v[3].x, v[1].y + v[3].y);
    float2 t3 = make_float2(v[1].x - v[3].x, v[1].y - v[3].y);
    v[0] = make_float2(t0.x + t2.x, t0.y + t2.y);
    v[2] = make_float2(t0.x - t2.x, t0.y - t2.y);
    if (DIR < 0) {
        v[1] = make_float2(t1.x + t3.y, t1.y - t3.x);
        v[3] = make_float2(t1.x - t3.y, t1.y + t3.x);
    } else {
        v[1] = make_float2(t1.x - t3.y, t1.y + t3.x);
        v[3] = make_float2(t1.x + t3.y, t1.y - t3.x);
    }
}

template <int DIR>
__device__ inline void fft8v(float2 v[8]) {
    float2 e[4] = { v[0], v[2], v[4], v[6] };
    float2 o[4] = { v[1], v[3], v[5], v[7] };
    fft4v<DIR>(e);
    fft4v<DIR>(o);
    const float c = 0.70710678118654752f;
    float2 o0 = o[0], o1, o2, o3;
    if (DIR < 0) {
        o1 = make_float2(c * (o[1].x + o[1].y), c * (o[1].y - o[1].x));
        o2 = make_float2(o[2].y, -o[2].x);
        o3 = make_float2(c * (o[3].y - o[3].x), -c * (o[3].x + o[3].y));
    } else {
        o1 = make_float2(c * (o[1].x - o[1].y), c * (o[1].y + o[1].x));
        o2 = make_float2(-o[2].y, o[2].x);
        o3 = make_float2(-c * (o[3].x + o[3].y), c * (o[3].x - o[3].y));
    }
    v[0] = make_float2(e[0].x + o0.x, e[0].y + o0.y);
    v[4] = make_float2(e[0].x - o0.x, e[0].y - o0.y);
    v[1] = make_float2(e[1].x + o1.x, e[1].y + o1.y);
    v[5] = make_float2(e[1].x - o1.x, e[1].y - o1.y);
    v[2] = make_float2(e[2].x + o2.x, e[2].y + o2.y);
    v[6] = make_float2(e[2].x - o2.x, e[2].y - o2.y);
    v[3] = make_float2(e[3].x + o3.x, e[3].y + o3.y);
    v[7] = make_float2(e[3].x - o3.x, e[3].y - o3.y);
}

// ---------------------------------------------------------------------------
// Stockham radix-8 stage: src -> dst, 256 threads, one butterfly each.
// ---------------------------------------------------------------------------
template <int DIR, int NSs>
__device__ inline void stage8(const float* __restrict__ reS, const float* __restrict__ imS,
                              float* __restrict__ reD, float* __restrict__ imD, int tid) {
    int j = tid;
    float2 v[8];
    #pragma unroll
    for (int r = 0; r < 8; ++r) {
        int a = IDX(j + (r << 8));
        v[r] = make_float2(reS[a], imS[a]);
    }
    if (NSs > 1) {
        float ang = (float)DIR * (TWO_PI_F / (8.0f * (float)NSs)) * (float)(j & (NSs - 1));
        float2 w1; __sincosf(ang, &w1.y, &w1.x);
        float2 w = w1;
        v[1] = cmul(v[1], w);
        #pragma unroll
        for (int r = 2; r < 8; ++r) { w = cmul(w, w1); v[r] = cmul(v[r], w); }
    }
    fft8v<DIR>(v);
    int idxD = ((j & ~(NSs - 1)) << 3) + (j & (NSs - 1));
    #pragma unroll
    for (int r = 0; r < 8; ++r) {
        int a = IDX(idxD + r * NSs);
        reD[a] = v[r].x;
        imD[a] = v[r].y;
    }
}

// Final radix-4 stage, NS=512: threads handle j = tid and tid+256. Natural order.
template <int DIR>
__device__ inline void stage4_512(const float* __restrict__ reS, const float* __restrict__ imS,
                                  float* __restrict__ reD, float* __restrict__ imD, int tid) {
    #pragma unroll
    for (int h = 0; h < 2; ++h) {
        int j = tid + (h << 8);
        float2 v[4];
        #pragma unroll
        for (int r = 0; r < 4; ++r) {
            int a = IDX(j + (r << 9));
            v[r] = make_float2(reS[a], imS[a]);
        }
        float ang = (float)DIR * (TWO_PI_F / 2048.0f) * (float)j;
        float2 w1; __sincosf(ang, &w1.y, &w1.x);
        float2 w2 = cmul(w1, w1);
        float2 w3 = cmul(w2, w1);
        v[1] = cmul(v[1], w1);
        v[2] = cmul(v[2], w2);
        v[3] = cmul(v[3], w3);
        fft4v<DIR>(v);
        #pragma unroll
        for (int r = 0; r < 4; ++r) {
            int a = IDX(j + (r << 9));
            reD[a] = v[r].x;
            imD[a] = v[r].y;
        }
    }
}

template <int DIR>
__device__ inline void fft2048(float* reA, float* imA, float* reB, float* imB, int tid) {
    stage8<DIR, 1>(reA, imA, reB, imB, tid);  __syncthreads();
    stage8<DIR, 8>(reB, imB, reA, imA, tid);  __syncthreads();
    stage8<DIR, 64>(reA, imA, reB, imB, tid); __syncthreads();
    stage4_512<DIR>(reB, imB, reA, imA, tid); __syncthreads();
}

// ---------------------------------------------------------------------------
// STFT: one block per frame (696 total). Real-packing + 2048-pt FFT + unpack.
// ---------------------------------------------------------------------------
__global__ __launch_bounds__(256) void stft_kernel(
    const float* __restrict__ x, const float* __restrict__ s,
    float2* __restrict__ Xs, float2* __restrict__ Ss) {
    __shared__ float reA[LDSN], imA[LDSN], reB[LDSN], imB[LDSN];
    int tid = threadIdx.x;
    int fid = blockIdx.x;
    const float* src;
    float2* dst;
    if (fid < NB * NC * NT) {
        int b = fid / (NC * NT);
        int r = fid % (NC * NT);
        int c = r / NT;
        int t = r % NT;
        src = x + (size_t)((b * NC + c) * NS + t * HOP);
        dst = Xs + (size_t)((b * NC + c) * NT + t) * NF;
    } else {
        int g  = fid - NB * NC * NT;
        int bs = g / (NC * NT);
        int r  = g % (NC * NT);
        int c  = r / NT;
        int t  = r % NT;
        src = s + (size_t)((bs * NC + c) * NS + t * HOP);
        dst = Ss + (size_t)((bs * NC + c) * NT + t) * NF;
    }
    const float2* s2 = (const float2*)src;
    for (int n = tid; n < 2048; n += 256) {
        float2 v = s2[n];
        float we = __sinf((float)n * (PI_F / 2048.0f));
        float wo = __sinf((float)(2 * n + 1) * (PI_F / 4096.0f));
        int a = IDX(n);
        reA[a] = v.x * we;
        imA[a] = v.y * wo;
    }
    __syncthreads();
    fft2048<-1>(reA, imA, reB, imB, tid);
    for (int k = tid; k <= 1024; k += 256) {
        int a1 = IDX(k);
        int a2 = IDX((2048 - k) & 2047);
        float2 Za = make_float2(reA[a1], imA[a1]);
        float2 Zb = make_float2(reA[a2], imA[a2]);
        if (k == 0) {
            dst[0]    = make_float2(Za.x + Za.y, 0.f);
            dst[2048] = make_float2(Za.x - Za.y, 0.f);
        } else {
            float2 Ze = make_float2(0.5f * (Za.x + Zb.x),  0.5f * (Za.y - Zb.y));
            float2 Zo = make_float2(0.5f * (Za.y + Zb.y), -0.5f * (Za.x - Zb.x));
            float ang = -(PI_F / 2048.0f) * (float)k;
            float2 W; __sincosf(ang, &W.y, &W.x);
            float2 WZo = cmul(W, Zo);
            dst[k] = make_float2(Ze.x + WZo.x, Ze.y + WZo.y);
            if (k < 1024)
                dst[2048 - k] = make_float2(Ze.x - WZo.x, -(Ze.y - WZo.y));
        }
    }
}

// ---------------------------------------------------------------------------
// Fused MVDR with LDS transpose staging. Block = (bs, 8 f). Coalesced loads
// of the (8ch x 32t x 8f) tile into LDS; compute threads (lane=(fpair<<5)|t)
// read per-t values from LDS; causal PSD via width-32 segmented shuffle scan;
// 4x4 complex Gauss-Jordan; beamform; stage Es tile in LDS; coalesced store.
// LDS rows padded to 9 float2 -> max 2-way bank aliasing (free on wave64).
// ---------------------------------------------------------------------------
__global__ __launch_bounds__(256) void mvdr2_kernel(
    const float2* __restrict__ Xs, const float2* __restrict__ Ss,
    float2* __restrict__ Es) {
    __shared__ float2 ldsS[4][32][9];
    __shared__ float2 ldsX[4][32][9];
    __shared__ float2 ldsE[4][32][9];
    int tid = threadIdx.x;
    int blk = blockIdx.x;
    int bs  = blk / FCHUNKS;
    int f0  = (blk % FCHUNKS) * 8;
    int b   = bs >> 1;

    // ---- coalesced stage-in: 8 q-planes (4 S + 4 X) x 32 t x 8 fi ----
    for (int idx = tid; idx < 2048; idx += 256) {
        int fi = idx & 7;
        int tt = (idx >> 3) & 31;
        int q  = idx >> 8;       // 0..7
        int c  = q & 3;
        int f  = f0 + fi;
        float2 val = make_float2(0.f, 0.f);
        if (tt < NT && f < NF) {
            val = (q >= 4) ? Xs[(size_t)((b  * NC + c) * NT + tt) * NF + f]
                           : Ss[(size_t)((bs * NC + c) * NT + tt) * NF + f];
        }
        if (q >= 4) ldsX[c][tt][fi] = val; else ldsS[c][tt][fi] = val;
    }
    __syncthreads();

    int lane  = tid & 63;
    int wave  = tid >> 6;
    int t     = lane & 31;
    int fpair = lane >> 5;
    int fi    = wave * 2 + fpair;
    int f     = f0 + fi;
    bool valid = (t < NT) && (f < NF);

    float2 Sv[4], Xv[4], Nv[4];
    #pragma unroll
    for (int c = 0; c < 4; ++c) {
        Sv[c] = ldsS[c][t][fi];
        Xv[c] = ldsX[c][t][fi];
        Nv[c] = make_float2(Xv[c].x - Sv[c].x, Xv[c].y - Sv[c].y);
    }

    // 32 scan values: [0..3] ps diag, [4..15] ps off re/im, [16..19] pn diag,
    // [20..31] pn off re/im. Pairs: (0,1),(0,2),(0,3),(1,2),(1,3),(2,3).
    float v[32];
    #pragma unroll
    for (int c = 0; c < 4; ++c) {
        v[c]      = Sv[c].x * Sv[c].x + Sv[c].y * Sv[c].y;
        v[16 + c] = Nv[c].x * Nv[c].x + Nv[c].y * Nv[c].y;
    }
    constexpr int PI6[6] = {0, 0, 0, 1, 1, 2};
    constexpr int PJ6[6] = {1, 2, 3, 2, 3, 3};
    #pragma unroll
    for (int p = 0; p < 6; ++p) {
        float2 d = cmulc(Sv[PI6[p]], Sv[PJ6[p]]);
        v[4 + 2 * p] = d.x; v[5 + 2 * p] = d.y;
        d = cmulc(Nv[PI6[p]], Nv[PJ6[p]]);
        v[20 + 2 * p] = d.x; v[21 + 2 * p] = d.y;
    }

    // Inclusive scan over t within each 32-lane segment.
    #pragma unroll
    for (int dlt = 1; dlt < 32; dlt <<= 1) {
        #pragma unroll
        for (int k = 0; k < 32; ++k) {
            float up = __shfl_up(v[k], (unsigned)dlt, 32);
            if (t >= dlt) v[k] += up;
        }
    }

    // Rebuild normalized Hermitian matrices.
    float ic = 1.0f / (float)(t + 1);
    float2 ps[4][4], pn[4][4];
    #pragma unroll
    for (int c = 0; c < 4; ++c) {
        ps[c][c] = make_float2(v[c] * ic, 0.f);
        pn[c][c] = make_float2(v[16 + c] * ic, 0.f);
    }
    #pragma unroll
    for (int p = 0; p < 6; ++p) {
        int i = PI6[p], j = PJ6[p];
        float re = v[4 + 2 * p] * ic, im = v[5 + 2 * p] * ic;
        ps[i][j] = make_float2(re, im);
        ps[j][i] = make_float2(re, -im);
        re = v[20 + 2 * p] * ic; im = v[21 + 2 * p] * ic;
        pn[i][j] = make_float2(re, im);
        pn[j][i] = make_float2(re, -im);
    }

    float tr_n = pn[0][0].x + pn[1][1].x + pn[2][2].x + pn[3][3].x;
    float eps  = tr_n * 1e-7f + 1e-8f;
    #pragma unroll
    for (int i = 0; i < 4; ++i) pn[i][i].x += eps;

    // Gauss-Jordan: [pn | I] -> [I | inv(pn)] (HPD, no pivoting needed).
    float2 M[4][8];
    #pragma unroll
    for (int i = 0; i < 4; ++i) {
        #pragma unroll
        for (int j = 0; j < 4; ++j) M[i][j] = pn[i][j];
        #pragma unroll
        for (int j = 0; j < 4; ++j) M[i][4 + j] = make_float2((i == j) ? 1.f : 0.f, 0.f);
    }
    #pragma unroll
    for (int col = 0; col < 4; ++col) {
        float2 piv = M[col][col];
        float  idd = 1.0f / (piv.x * piv.x + piv.y * piv.y);
        float2 pinv = make_float2(piv.x * idd, -piv.y * idd);
        #pragma unroll
        for (int j = 0; j < 8; ++j) M[col][j] = cmul(M[col][j], pinv);
        #pragma unroll
        for (int rr = 0; rr < 4; ++rr) {
            if (rr == col) continue;
            float2 fac = M[rr][col];
            #pragma unroll
            for (int j = 0; j < 8; ++j) {
                float2 d = cmul(fac, M[col][j]);
                M[rr][j].x -= d.x; M[rr][j].y -= d.y;
            }
        }
    }

    // num = inv(pn) @ ps
    float2 num[4][4];
    #pragma unroll
    for (int i = 0; i < 4; ++i)
        #pragma unroll
        for (int j = 0; j < 4; ++j) {
            float2 acc = make_float2(0.f, 0.f);
            #pragma unroll
            for (int k = 0; k < 4; ++k) {
                float2 d = cmul(M[i][4 + k], ps[k][j]);
                acc.x += d.x; acc.y += d.y;
            }
            num[i][j] = acc;
        }
    float2 tr = make_float2(num[0][0].x + num[1][1].x + num[2][2].x + num[3][3].x + 1e-8f,
                            num[0][0].y + num[1][1].y + num[2][2].y + num[3][3].y);
    float itd = 1.0f / (tr.x * tr.x + tr.y * tr.y);
    float2 tinv = make_float2(tr.x * itd, -tr.y * itd);

    #pragma unroll
    for (int bo = 0; bo < 4; ++bo) {
        float2 e = make_float2(0.f, 0.f);
        #pragma unroll
        for (int a = 0; a < 4; ++a) {
            float2 w = cmul(num[a][bo], tinv);
            float2 d = cmulc(Xv[a], w);  // X * conj(ws)
            e.x += d.x; e.y += d.y;
        }
        ldsE[bo][t][fi] = e;
    }
    __syncthreads();

    // ---- coalesced stage-out: 4 bo x 32 t x 8 fi ----
    for (int idx = tid; idx < 1024; idx += 256) {
        int fi2 = idx & 7;
        int tt  = (idx >> 3) & 31;
        int bo  = idx >> 8;
        int ff  = f0 + fi2;
        if (tt < NT && ff < NF)
            Es[(size_t)((bs * NC + bo) * NT + tt) * NF + ff] = ldsE[bo][tt][fi2];
    }
}

// ---------------------------------------------------------------------------
// iSTFT: one block per frame (464). Pack bins, inverse FFT, window, write.
// ---------------------------------------------------------------------------
__global__ __launch_bounds__(256) void istft_kernel(
    const float2* __restrict__ Es, float* __restrict__ Fr) {
    __shared__ float reA[LDSN], imA[LDSN], reB[LDSN], imB[LDSN];
    int tid = threadIdx.x;
    int fid = blockIdx.x;
    int bs = fid / (NC * NT);
    int r  = fid % (NC * NT);
    int c  = r / NT;
    int t  = r % NT;
    const float2* src = Es + (size_t)((bs * NC + c) * NT + t) * NF;
    for (int k = tid; k <= 1024; k += 256) {
        float2 A = src[k];
        float2 B = src[2048 - k];
        float2 Ze = make_float2(0.5f * (A.x + B.x), 0.5f * (A.y - B.y));
        float2 D  = make_float2(0.5f * (A.x - B.x), 0.5f * (A.y + B.y));
        float ang = (PI_F / 2048.0f) * (float)k;
        float2 W; __sincosf(ang, &W.y, &W.x);
        float2 Zo = cmul(W, D);
        int a1 = IDX(k);
        reA[a1] = Ze.x - Zo.y;
        imA[a1] = Ze.y + Zo.x;
        if (k > 0 && k < 1024) {
            int a2 = IDX(2048 - k);
            reA[a2] = Ze.x + Zo.y;
            imA[a2] = -Ze.y + Zo.x;
        }
    }
    __syncthreads();
    fft2048<1>(reA, imA, reB, imB, tid);
    float2* d2 = (float2*)(Fr + (size_t)((bs * NC + c) * NT + t) * NFFT);
    for (int n = tid; n < 2048; n += 256) {
        int a = IDX(n);
        float we = __sinf((float)n * (PI_F / 2048.0f)) * (1.0f / 2048.0f);
        float wo = __sinf((float)(2 * n + 1) * (PI_F / 4096.0f)) * (1.0f / 2048.0f);
        d2[n] = make_float2(reA[a] * we, imA[a] * wo);
    }
}

// ---------------------------------------------------------------------------
// Overlap-add + window-squared normalization. One thread per output sample.
// ---------------------------------------------------------------------------
__global__ __launch_bounds__(256) void ola_kernel(
    const float* __restrict__ Fr, float* __restrict__ out) {
    int idx = blockIdx.x * 256 + threadIdx.x;
    const int total = NBS * NC * NS;
    if (idx >= total) return;
    int p  = idx & (NS - 1);
    int ch = idx >> 15;
    int t1 = p >> 10;
    if (t1 > NT - 1) t1 = NT - 1;
    int t0 = (p >= NFFT) ? ((p - (NFFT - 1) + (HOP - 1)) >> 10) : 0;
    float acc = 0.f, wacc = 0.f;
    for (int t = t0; t <= t1; ++t) {
        int   j = p - (t << 10);
        float w = __sinf((float)j * (PI_F / 4096.0f));
        acc  += Fr[((size_t)(ch * NT + t) << 12) + j];
        wacc += w * w;
    }
    out[idx] = acc / fmaxf(wacc, 1e-8f);
}

// ---------------------------------------------------------------------------
extern "C" void kernel_launch(void* const* d_in, const int* in_sizes, int n_in,
                              void* d_out, int out_size, void* d_ws, size_t ws_size,
                              hipStream_t stream) {
    const float* x = (const float*)d_in[0];  // (2,4,32768)
    const float* s = (const float*)d_in[1];  // (2,2,4,32768)
    float* out = (float*)d_out;              // (2,2,4,32768)

    const size_t XS_N = (size_t)NB  * NC * NT * NF;   // float2
    const size_t SS_N = (size_t)NBS * NC * NT * NF;   // float2
    float2* Xs = (float2*)d_ws;
    float2* Ss = Xs + XS_N;
    float2* Es = Ss + SS_N;
    float*  Fr = (float*)(Es + SS_N);

    stft_kernel<<<NB * NC * NT + NBS * NC * NT, 256, 0, stream>>>(x, s, Xs, Ss);

    mvdr2_kernel<<<NBS * FCHUNKS, 256, 0, stream>>>(Xs, Ss, Es);

    istft_kernel<<<NBS * NC * NT, 256, 0, stream>>>(Es, Fr);

    int ola_total = NBS * NC * NS;   // 524,288
    ola_kernel<<<(ola_total + 255) / 256, 256, 0, stream>>>(Fr, out);
}

// Round 7
// 43.966 us; speedup vs baseline: 1.1291x; 1.1291x over previous
//
#include <hip/hip_runtime.h>

// MVDR beamformer pipeline: STFT -> causal PSD (DPP scan) -> Souden MVDR (GJ) -> beamform -> iSTFT
static constexpr int NFFT = 4096;
static constexpr int HOP  = 1024;
static constexpr int NF   = 2049;   // rfft bins
static constexpr int NT   = 29;     // frames
static constexpr int NS   = 32768;  // samples per channel
static constexpr int NB   = 2;      // batch
static constexpr int NSrc = 2;      // sources
static constexpr int NC   = 4;      // channels
static constexpr int NBS  = NB * NSrc;
static constexpr int FCHUNKS = (NF + 7) / 8;  // 257 f-chunks of 8 per block

#define PI_F     3.14159265358979323846f
#define TWO_PI_F 6.28318530717958647692f

// LDS padding: one extra float every 16 -> breaks all power-of-2 stride conflicts
#define IDX(a) ((a) + ((a) >> 4))
static constexpr int LDSN = 2048 + 128;  // padded length

__device__ inline float2 cmul(float2 a, float2 b) {
    return make_float2(a.x * b.x - a.y * b.y, a.x * b.y + a.y * b.x);
}
// a * conj(b)
__device__ inline float2 cmulc(float2 a, float2 b) {
    return make_float2(a.x * b.x + a.y * b.y, a.y * b.x - a.x * b.y);
}

// DPP-shifted source (0 for masked/out-of-range lanes): pure-VALU scan step.
template <int CTRL, int RMASK>
__device__ __forceinline__ float dpp0(float x) {
    return __int_as_float(__builtin_amdgcn_update_dpp(
        0, __float_as_int(x), CTRL, RMASK, 0xF, true));
}

// ---------------------------------------------------------------------------
// 4- and 8-point DFT building blocks. DIR=-1 forward (e^{-i}), +1 inverse.
// ---------------------------------------------------------------------------
template <int DIR>
__device__ inline void fft4v(float2 v[4]) {
    float2 t0 = make_float2(v[0].x + v[2].x, v[0].y + v[2].y);
    float2 t1 = make_float2(v[0].x - v[2].x, v[0].y - v[2].y);
    float2 t2 = make_float2(v[1].x + v[3].x, v[1].y + v[3].y);
    float2 t3 = make_float2(v[1].x - v[3].x, v[1].y - v[3].y);
    v[0] = make_float2(t0.x + t2.x, t0.y + t2.y);
    v[2] = make_float2(t0.x - t2.x, t0.y - t2.y);
    if (DIR < 0) {
        v[1] = make_float2(t1.x + t3.y, t1.y - t3.x);
        v[3] = make_float2(t1.x - t3.y, t1.y + t3.x);
    } else {
        v[1] = make_float2(t1.x - t3.y, t1.y + t3.x);
        v[3] = make_float2(t1.x + t3.y, t1.y - t3.x);
    }
}

template <int DIR>
__device__ inline void fft8v(float2 v[8]) {
    float2 e[4] = { v[0], v[2], v[4], v[6] };
    float2 o[4] = { v[1], v[3], v[5], v[7] };
    fft4v<DIR>(e);
    fft4v<DIR>(o);
    const float c = 0.70710678118654752f;
    float2 o0 = o[0], o1, o2, o3;
    if (DIR < 0) {
        o1 = make_float2(c * (o[1].x + o[1].y), c * (o[1].y - o[1].x));
        o2 = make_float2(o[2].y, -o[2].x);
        o3 = make_float2(c * (o[3].y - o[3].x), -c * (o[3].x + o[3].y));
    } else {
        o1 = make_float2(c * (o[1].x - o[1].y), c * (o[1].y + o[1].x));
        o2 = make_float2(-o[2].y, o[2].x);
        o3 = make_float2(-c * (o[3].x + o[3].y), c * (o[3].x - o[3].y));
    }
    v[0] = make_float2(e[0].x + o0.x, e[0].y + o0.y);
    v[4] = make_float2(e[0].x - o0.x, e[0].y - o0.y);
    v[1] = make_float2(e[1].x + o1.x, e[1].y + o1.y);
    v[5] = make_float2(e[1].x - o1.x, e[1].y - o1.y);
    v[2] = make_float2(e[2].x + o2.x, e[2].y + o2.y);
    v[6] = make_float2(e[2].x - o2.x, e[2].y - o2.y);
    v[3] = make_float2(e[3].x + o3.x, e[3].y + o3.y);
    v[7] = make_float2(e[3].x - o3.x, e[3].y - o3.y);
}

// ---------------------------------------------------------------------------
// Stockham radix-8 stage: src -> dst, 256 threads, one butterfly each.
// ---------------------------------------------------------------------------
template <int DIR, int NSs>
__device__ inline void stage8(const float* __restrict__ reS, const float* __restrict__ imS,
                              float* __restrict__ reD, float* __restrict__ imD, int tid) {
    int j = tid;
    float2 v[8];
    #pragma unroll
    for (int r = 0; r < 8; ++r) {
        int a = IDX(j + (r << 8));
        v[r] = make_float2(reS[a], imS[a]);
    }
    if (NSs > 1) {
        float ang = (float)DIR * (TWO_PI_F / (8.0f * (float)NSs)) * (float)(j & (NSs - 1));
        float2 w1; __sincosf(ang, &w1.y, &w1.x);
        float2 w = w1;
        v[1] = cmul(v[1], w);
        #pragma unroll
        for (int r = 2; r < 8; ++r) { w = cmul(w, w1); v[r] = cmul(v[r], w); }
    }
    fft8v<DIR>(v);
    int idxD = ((j & ~(NSs - 1)) << 3) + (j & (NSs - 1));
    #pragma unroll
    for (int r = 0; r < 8; ++r) {
        int a = IDX(idxD + r * NSs);
        reD[a] = v[r].x;
        imD[a] = v[r].y;
    }
}

// Final radix-4 stage, NS=512: threads handle j = tid and tid+256. Natural order.
template <int DIR>
__device__ inline void stage4_512(const float* __restrict__ reS, const float* __restrict__ imS,
                                  float* __restrict__ reD, float* __restrict__ imD, int tid) {
    #pragma unroll
    for (int h = 0; h < 2; ++h) {
        int j = tid + (h << 8);
        float2 v[4];
        #pragma unroll
        for (int r = 0; r < 4; ++r) {
            int a = IDX(j + (r << 9));
            v[r] = make_float2(reS[a], imS[a]);
        }
        float ang = (float)DIR * (TWO_PI_F / 2048.0f) * (float)j;
        float2 w1; __sincosf(ang, &w1.y, &w1.x);
        float2 w2 = cmul(w1, w1);
        float2 w3 = cmul(w2, w1);
        v[1] = cmul(v[1], w1);
        v[2] = cmul(v[2], w2);
        v[3] = cmul(v[3], w3);
        fft4v<DIR>(v);
        #pragma unroll
        for (int r = 0; r < 4; ++r) {
            int a = IDX(j + (r << 9));
            reD[a] = v[r].x;
            imD[a] = v[r].y;
        }
    }
}

template <int DIR>
__device__ inline void fft2048(float* reA, float* imA, float* reB, float* imB, int tid) {
    stage8<DIR, 1>(reA, imA, reB, imB, tid);  __syncthreads();
    stage8<DIR, 8>(reB, imB, reA, imA, tid);  __syncthreads();
    stage8<DIR, 64>(reA, imA, reB, imB, tid); __syncthreads();
    stage4_512<DIR>(reB, imB, reA, imA, tid); __syncthreads();
}

// ---------------------------------------------------------------------------
// STFT: one block per frame (696 total). Real-packing + 2048-pt FFT + unpack.
// ---------------------------------------------------------------------------
__global__ __launch_bounds__(256) void stft_kernel(
    const float* __restrict__ x, const float* __restrict__ s,
    float2* __restrict__ Xs, float2* __restrict__ Ss) {
    __shared__ float reA[LDSN], imA[LDSN], reB[LDSN], imB[LDSN];
    int tid = threadIdx.x;
    int fid = blockIdx.x;
    const float* src;
    float2* dst;
    if (fid < NB * NC * NT) {
        int b = fid / (NC * NT);
        int r = fid % (NC * NT);
        int c = r / NT;
        int t = r % NT;
        src = x + (size_t)((b * NC + c) * NS + t * HOP);
        dst = Xs + (size_t)((b * NC + c) * NT + t) * NF;
    } else {
        int g  = fid - NB * NC * NT;
        int bs = g / (NC * NT);
        int r  = g % (NC * NT);
        int c  = r / NT;
        int t  = r % NT;
        src = s + (size_t)((bs * NC + c) * NS + t * HOP);
        dst = Ss + (size_t)((bs * NC + c) * NT + t) * NF;
    }
    const float2* s2 = (const float2*)src;
    for (int n = tid; n < 2048; n += 256) {
        float2 v = s2[n];
        float we = __sinf((float)n * (PI_F / 2048.0f));
        float wo = __sinf((float)(2 * n + 1) * (PI_F / 4096.0f));
        int a = IDX(n);
        reA[a] = v.x * we;
        imA[a] = v.y * wo;
    }
    __syncthreads();
    fft2048<-1>(reA, imA, reB, imB, tid);
    for (int k = tid; k <= 1024; k += 256) {
        int a1 = IDX(k);
        int a2 = IDX((2048 - k) & 2047);
        float2 Za = make_float2(reA[a1], imA[a1]);
        float2 Zb = make_float2(reA[a2], imA[a2]);
        if (k == 0) {
            dst[0]    = make_float2(Za.x + Za.y, 0.f);
            dst[2048] = make_float2(Za.x - Za.y, 0.f);
        } else {
            float2 Ze = make_float2(0.5f * (Za.x + Zb.x),  0.5f * (Za.y - Zb.y));
            float2 Zo = make_float2(0.5f * (Za.y + Zb.y), -0.5f * (Za.x - Zb.x));
            float ang = -(PI_F / 2048.0f) * (float)k;
            float2 W; __sincosf(ang, &W.y, &W.x);
            float2 WZo = cmul(W, Zo);
            dst[k] = make_float2(Ze.x + WZo.x, Ze.y + WZo.y);
            if (k < 1024)
                dst[2048 - k] = make_float2(Ze.x - WZo.x, -(Ze.y - WZo.y));
        }
    }
}

// ---------------------------------------------------------------------------
// Fused MVDR. Block = (bs, 8 f). Coalesced LDS stage-in of (8ch x 32t x 8f);
// compute thread (t,fi): causal PSD via pure-VALU DPP segmented scan (32-lane
// segments, lanes=t); Gauss-Jordan 4x4 Hermitian inverse (reduced column
// range); epilogue via z = ipn^H X, complex trace, e = conj(1/tr) * ps @ z.
// E tile staged back through ldsS (each thread writes only slots it alone
// read) and stored coalesced.
// ---------------------------------------------------------------------------
__global__ __launch_bounds__(256) void mvdr2_kernel(
    const float2* __restrict__ Xs, const float2* __restrict__ Ss,
    float2* __restrict__ Es) {
    __shared__ float2 ldsS[4][32][9];   // also reused as E-staging
    __shared__ float2 ldsX[4][32][9];
    int tid = threadIdx.x;
    int blk = blockIdx.x;
    int bs  = blk / FCHUNKS;
    int f0  = (blk % FCHUNKS) * 8;
    int b   = bs >> 1;

    // ---- coalesced stage-in: 8 q-planes (4 S + 4 X) x 32 t x 8 fi ----
    for (int idx = tid; idx < 2048; idx += 256) {
        int fi = idx & 7;
        int tt = (idx >> 3) & 31;
        int q  = idx >> 8;       // 0..7
        int c  = q & 3;
        int f  = f0 + fi;
        float2 val = make_float2(0.f, 0.f);
        if (tt < NT && f < NF) {
            val = (q >= 4) ? Xs[(size_t)((b  * NC + c) * NT + tt) * NF + f]
                           : Ss[(size_t)((bs * NC + c) * NT + tt) * NF + f];
        }
        if (q >= 4) ldsX[c][tt][fi] = val; else ldsS[c][tt][fi] = val;
    }
    __syncthreads();

    int lane  = tid & 63;
    int wave  = tid >> 6;
    int t     = lane & 31;
    int fpair = lane >> 5;
    int fi    = wave * 2 + fpair;

    float2 Sv[4], Xv[4], Nv[4];
    #pragma unroll
    for (int c = 0; c < 4; ++c) {
        Sv[c] = ldsS[c][t][fi];
        Xv[c] = ldsX[c][t][fi];
        Nv[c] = make_float2(Xv[c].x - Sv[c].x, Xv[c].y - Sv[c].y);
    }

    // 32 scan values: [0..3] ps diag, [4..15] ps off re/im, [16..19] pn diag,
    // [20..31] pn off re/im. Pairs: (0,1),(0,2),(0,3),(1,2),(1,3),(2,3).
    float v[32];
    #pragma unroll
    for (int c = 0; c < 4; ++c) {
        v[c]      = Sv[c].x * Sv[c].x + Sv[c].y * Sv[c].y;
        v[16 + c] = Nv[c].x * Nv[c].x + Nv[c].y * Nv[c].y;
    }
    constexpr int PI6[6] = {0, 0, 0, 1, 1, 2};
    constexpr int PJ6[6] = {1, 2, 3, 2, 3, 3};
    #pragma unroll
    for (int p = 0; p < 6; ++p) {
        float2 d = cmulc(Sv[PI6[p]], Sv[PJ6[p]]);
        v[4 + 2 * p] = d.x; v[5 + 2 * p] = d.y;
        d = cmulc(Nv[PI6[p]], Nv[PJ6[p]]);
        v[20 + 2 * p] = d.x; v[21 + 2 * p] = d.y;
    }

    // Segmented (32-lane) inclusive scan over t, pure VALU via DPP:
    // row_shr 1,2,4,8 within 16-lane rows, then row_bcast15 into odd rows.
    #pragma unroll
    for (int k = 0; k < 32; ++k) v[k] += dpp0<0x111, 0xF>(v[k]);
    #pragma unroll
    for (int k = 0; k < 32; ++k) v[k] += dpp0<0x112, 0xF>(v[k]);
    #pragma unroll
    for (int k = 0; k < 32; ++k) v[k] += dpp0<0x114, 0xF>(v[k]);
    #pragma unroll
    for (int k = 0; k < 32; ++k) v[k] += dpp0<0x118, 0xF>(v[k]);
    #pragma unroll
    for (int k = 0; k < 32; ++k) v[k] += dpp0<0x142, 0xA>(v[k]);

    // Rebuild normalized Hermitian matrices. ps as full 4x4; pn into GJ M.
    float ic = 1.0f / (float)(t + 1);
    float2 ps[4][4];
    float2 M[4][8];
    #pragma unroll
    for (int c = 0; c < 4; ++c) {
        ps[c][c]   = make_float2(v[c] * ic, 0.f);
        M[c][c]    = make_float2(v[16 + c] * ic, 0.f);
        #pragma unroll
        for (int j = 0; j < 4; ++j)
            M[c][4 + j] = make_float2((c == j) ? 1.f : 0.f, 0.f);
    }
    #pragma unroll
    for (int p = 0; p < 6; ++p) {
        int i = PI6[p], j = PJ6[p];
        float re = v[4 + 2 * p] * ic, im = v[5 + 2 * p] * ic;
        ps[i][j] = make_float2(re, im);
        ps[j][i] = make_float2(re, -im);
        re = v[20 + 2 * p] * ic; im = v[21 + 2 * p] * ic;
        M[i][j] = make_float2(re, im);
        M[j][i] = make_float2(re, -im);
    }

    // diagonal loading
    float eps = (M[0][0].x + M[1][1].x + M[2][2].x + M[3][3].x) * 1e-7f + 1e-8f;
    #pragma unroll
    for (int i = 0; i < 4; ++i) M[i][i].x += eps;

    // Gauss-Jordan [pn | I] -> [I | inv(pn)], updating only columns j > col
    // (left half becomes identity; those values are never read again).
    #pragma unroll
    for (int col = 0; col < 4; ++col) {
        float2 piv = M[col][col];
        float  idd = 1.0f / (piv.x * piv.x + piv.y * piv.y);
        float2 pinv = make_float2(piv.x * idd, -piv.y * idd);
        #pragma unroll
        for (int j = col + 1; j < 8; ++j) M[col][j] = cmul(M[col][j], pinv);
        #pragma unroll
        for (int rr = 0; rr < 4; ++rr) {
            if (rr == col) continue;
            float2 fac = M[rr][col];
            #pragma unroll
            for (int j = col + 1; j < 8; ++j) {
                float2 d = cmul(fac, M[col][j]);
                M[rr][j].x -= d.x; M[rr][j].y -= d.y;
            }
        }
    }

    // z_k = sum_a conj(ipn[a][k]) X_a   (ipn[i][k] = M[i][4+k])
    float2 z[4];
    #pragma unroll
    for (int k = 0; k < 4; ++k) {
        float2 acc = make_float2(0.f, 0.f);
        #pragma unroll
        for (int a = 0; a < 4; ++a) {
            float2 q = M[a][4 + k];
            acc.x += q.x * Xv[a].x + q.y * Xv[a].y;
            acc.y += q.x * Xv[a].y - q.y * Xv[a].x;
        }
        z[k] = acc;
    }

    // complex trace tr = 1e-8 + sum_{i,k} ipn[i][k] * ps[k][i]
    float2 trc = make_float2(1e-8f, 0.f);
    #pragma unroll
    for (int i = 0; i < 4; ++i)
        #pragma unroll
        for (int k = 0; k < 4; ++k) {
            float2 q = M[i][4 + k];
            float2 p = ps[k][i];
            trc.x += q.x * p.x - q.y * p.y;
            trc.y += q.x * p.y + q.y * p.x;
        }
    float ginv = 1.0f / (trc.x * trc.x + trc.y * trc.y);
    float2 g = make_float2(trc.x * ginv, trc.y * ginv);  // conj(1/trc)

    // e_bo = g * sum_k ps[bo][k] z_k ; stage into ldsS (own slots only).
    #pragma unroll
    for (int bo = 0; bo < 4; ++bo) {
        float2 u = make_float2(0.f, 0.f);
        #pragma unroll
        for (int k = 0; k < 4; ++k) {
            float2 d = cmul(ps[bo][k], z[k]);
            u.x += d.x; u.y += d.y;
        }
        ldsS[bo][t][fi] = cmul(g, u);
    }
    __syncthreads();

    // ---- coalesced stage-out: 4 bo x 32 t x 8 fi ----
    for (int idx = tid; idx < 1024; idx += 256) {
        int fi2 = idx & 7;
        int tt  = (idx >> 3) & 31;
        int bo  = idx >> 8;
        int ff  = f0 + fi2;
        if (tt < NT && ff < NF)
            Es[(size_t)((bs * NC + bo) * NT + tt) * NF + ff] = ldsS[bo][tt][fi2];
    }
}

// ---------------------------------------------------------------------------
// iSTFT: one block per frame (464). Pack bins, inverse FFT, window, write.
// ---------------------------------------------------------------------------
__global__ __launch_bounds__(256) void istft_kernel(
    const float2* __restrict__ Es, float* __restrict__ Fr) {
    __shared__ float reA[LDSN], imA[LDSN], reB[LDSN], imB[LDSN];
    int tid = threadIdx.x;
    int fid = blockIdx.x;
    int bs = fid / (NC * NT);
    int r  = fid % (NC * NT);
    int c  = r / NT;
    int t  = r % NT;
    const float2* src = Es + (size_t)((bs * NC + c) * NT + t) * NF;
    for (int k = tid; k <= 1024; k += 256) {
        float2 A = src[k];
        float2 B = src[2048 - k];
        float2 Ze = make_float2(0.5f * (A.x + B.x), 0.5f * (A.y - B.y));
        float2 D  = make_float2(0.5f * (A.x - B.x), 0.5f * (A.y + B.y));
        float ang = (PI_F / 2048.0f) * (float)k;
        float2 W; __sincosf(ang, &W.y, &W.x);
        float2 Zo = cmul(W, D);
        int a1 = IDX(k);
        reA[a1] = Ze.x - Zo.y;
        imA[a1] = Ze.y + Zo.x;
        if (k > 0 && k < 1024) {
            int a2 = IDX(2048 - k);
            reA[a2] = Ze.x + Zo.y;
            imA[a2] = -Ze.y + Zo.x;
        }
    }
    __syncthreads();
    fft2048<1>(reA, imA, reB, imB, tid);
    float2* d2 = (float2*)(Fr + (size_t)((bs * NC + c) * NT + t) * NFFT);
    for (int n = tid; n < 2048; n += 256) {
        int a = IDX(n);
        float we = __sinf((float)n * (PI_F / 2048.0f)) * (1.0f / 2048.0f);
        float wo = __sinf((float)(2 * n + 1) * (PI_F / 4096.0f)) * (1.0f / 2048.0f);
        d2[n] = make_float2(reA[a] * we, imA[a] * wo);
    }
}

// ---------------------------------------------------------------------------
// Overlap-add + window-squared normalization. One thread per output sample.
// ---------------------------------------------------------------------------
__global__ __launch_bounds__(256) void ola_kernel(
    const float* __restrict__ Fr, float* __restrict__ out) {
    int idx = blockIdx.x * 256 + threadIdx.x;
    const int total = NBS * NC * NS;
    if (idx >= total) return;
    int p  = idx & (NS - 1);
    int ch = idx >> 15;
    int t1 = p >> 10;
    if (t1 > NT - 1) t1 = NT - 1;
    int t0 = (p >= NFFT) ? ((p - (NFFT - 1) + (HOP - 1)) >> 10) : 0;
    float acc = 0.f, wacc = 0.f;
    for (int t = t0; t <= t1; ++t) {
        int   j = p - (t << 10);
        float w = __sinf((float)j * (PI_F / 4096.0f));
        acc  += Fr[((size_t)(ch * NT + t) << 12) + j];
        wacc += w * w;
    }
    out[idx] = acc / fmaxf(wacc, 1e-8f);
}

// ---------------------------------------------------------------------------
extern "C" void kernel_launch(void* const* d_in, const int* in_sizes, int n_in,
                              void* d_out, int out_size, void* d_ws, size_t ws_size,
                              hipStream_t stream) {
    const float* x = (const float*)d_in[0];  // (2,4,32768)
    const float* s = (const float*)d_in[1];  // (2,2,4,32768)
    float* out = (float*)d_out;              // (2,2,4,32768)

    const size_t XS_N = (size_t)NB  * NC * NT * NF;   // float2
    const size_t SS_N = (size_t)NBS * NC * NT * NF;   // float2
    float2* Xs = (float2*)d_ws;
    float2* Ss = Xs + XS_N;
    float2* Es = Ss + SS_N;
    float*  Fr = (float*)(Es + SS_N);

    stft_kernel<<<NB * NC * NT + NBS * NC * NT, 256, 0, stream>>>(x, s, Xs, Ss);

    mvdr2_kernel<<<NBS * FCHUNKS, 256, 0, stream>>>(Xs, Ss, Es);

    istft_kernel<<<NBS * NC * NT, 256, 0, stream>>>(Es, Fr);

    int ola_total = NBS * NC * NS;   // 524,288
    ola_kernel<<<(ola_total + 255) / 256, 256, 0, stream>>>(Fr, out);
}

// Round 8
// 43.756 us; speedup vs baseline: 1.1345x; 1.0048x over previous
//
#include <hip/hip_runtime.h>

// MVDR beamformer pipeline: STFT -> causal PSD (DPP scan) -> Souden MVDR (GJ) -> beamform -> iSTFT
static constexpr int NFFT = 4096;
static constexpr int HOP  = 1024;
static constexpr int NF   = 2049;   // rfft bins
static constexpr int NT   = 29;     // frames
static constexpr int NS   = 32768;  // samples per channel
static constexpr int NB   = 2;      // batch
static constexpr int NSrc = 2;      // sources
static constexpr int NC   = 4;      // channels
static constexpr int NBS  = NB * NSrc;
static constexpr int FCHUNKS = (NF + 7) / 8;  // 257 f-chunks of 8 per block

#define PI_F     3.14159265358979323846f
#define TWO_PI_F 6.28318530717958647692f

// LDS padding: one extra float every 16 -> breaks all power-of-2 stride conflicts
#define IDX(a) ((a) + ((a) >> 4))
static constexpr int LDSN = 2048 + 128;  // padded length

__device__ inline float2 cmul(float2 a, float2 b) {
    return make_float2(a.x * b.x - a.y * b.y, a.x * b.y + a.y * b.x);
}
// a * conj(b)
__device__ inline float2 cmulc(float2 a, float2 b) {
    return make_float2(a.x * b.x + a.y * b.y, a.y * b.x - a.x * b.y);
}

// DPP-shifted source (0 for masked/out-of-range lanes): pure-VALU scan step.
template <int CTRL, int RMASK>
__device__ __forceinline__ float dpp0(float x) {
    return __int_as_float(__builtin_amdgcn_update_dpp(
        0, __float_as_int(x), CTRL, RMASK, 0xF, true));
}

// ---------------------------------------------------------------------------
// 4- and 8-point DFT building blocks. DIR=-1 forward (e^{-i}), +1 inverse.
// ---------------------------------------------------------------------------
template <int DIR>
__device__ inline void fft4v(float2 v[4]) {
    float2 t0 = make_float2(v[0].x + v[2].x, v[0].y + v[2].y);
    float2 t1 = make_float2(v[0].x - v[2].x, v[0].y - v[2].y);
    float2 t2 = make_float2(v[1].x + v[3].x, v[1].y + v[3].y);
    float2 t3 = make_float2(v[1].x - v[3].x, v[1].y - v[3].y);
    v[0] = make_float2(t0.x + t2.x, t0.y + t2.y);
    v[2] = make_float2(t0.x - t2.x, t0.y - t2.y);
    if (DIR < 0) {
        v[1] = make_float2(t1.x + t3.y, t1.y - t3.x);
        v[3] = make_float2(t1.x - t3.y, t1.y + t3.x);
    } else {
        v[1] = make_float2(t1.x - t3.y, t1.y + t3.x);
        v[3] = make_float2(t1.x + t3.y, t1.y - t3.x);
    }
}

template <int DIR>
__device__ inline void fft8v(float2 v[8]) {
    float2 e[4] = { v[0], v[2], v[4], v[6] };
    float2 o[4] = { v[1], v[3], v[5], v[7] };
    fft4v<DIR>(e);
    fft4v<DIR>(o);
    const float c = 0.70710678118654752f;
    float2 o0 = o[0], o1, o2, o3;
    if (DIR < 0) {
        o1 = make_float2(c * (o[1].x + o[1].y), c * (o[1].y - o[1].x));
        o2 = make_float2(o[2].y, -o[2].x);
        o3 = make_float2(c * (o[3].y - o[3].x), -c * (o[3].x + o[3].y));
    } else {
        o1 = make_float2(c * (o[1].x - o[1].y), c * (o[1].y + o[1].x));
        o2 = make_float2(-o[2].y, o[2].x);
        o3 = make_float2(-c * (o[3].x + o[3].y), c * (o[3].x - o[3].y));
    }
    v[0] = make_float2(e[0].x + o0.x, e[0].y + o0.y);
    v[4] = make_float2(e[0].x - o0.x, e[0].y - o0.y);
    v[1] = make_float2(e[1].x + o1.x, e[1].y + o1.y);
    v[5] = make_float2(e[1].x - o1.x, e[1].y - o1.y);
    v[2] = make_float2(e[2].x + o2.x, e[2].y + o2.y);
    v[6] = make_float2(e[2].x - o2.x, e[2].y - o2.y);
    v[3] = make_float2(e[3].x + o3.x, e[3].y + o3.y);
    v[7] = make_float2(e[3].x - o3.x, e[3].y - o3.y);
}

// ---------------------------------------------------------------------------
// Stockham radix-8 stage: src -> dst, 256 threads, one butterfly each.
// ---------------------------------------------------------------------------
template <int DIR, int NSs>
__device__ inline void stage8(const float* __restrict__ reS, const float* __restrict__ imS,
                              float* __restrict__ reD, float* __restrict__ imD, int tid) {
    int j = tid;
    float2 v[8];
    #pragma unroll
    for (int r = 0; r < 8; ++r) {
        int a = IDX(j + (r << 8));
        v[r] = make_float2(reS[a], imS[a]);
    }
    if (NSs > 1) {
        float ang = (float)DIR * (TWO_PI_F / (8.0f * (float)NSs)) * (float)(j & (NSs - 1));
        float2 w1; __sincosf(ang, &w1.y, &w1.x);
        float2 w = w1;
        v[1] = cmul(v[1], w);
        #pragma unroll
        for (int r = 2; r < 8; ++r) { w = cmul(w, w1); v[r] = cmul(v[r], w); }
    }
    fft8v<DIR>(v);
    int idxD = ((j & ~(NSs - 1)) << 3) + (j & (NSs - 1));
    #pragma unroll
    for (int r = 0; r < 8; ++r) {
        int a = IDX(idxD + r * NSs);
        reD[a] = v[r].x;
        imD[a] = v[r].y;
    }
}

// Final radix-4 stage, NS=512: threads handle j = tid and tid+256. Natural order.
template <int DIR>
__device__ inline void stage4_512(const float* __restrict__ reS, const float* __restrict__ imS,
                                  float* __restrict__ reD, float* __restrict__ imD, int tid) {
    #pragma unroll
    for (int h = 0; h < 2; ++h) {
        int j = tid + (h << 8);
        float2 v[4];
        #pragma unroll
        for (int r = 0; r < 4; ++r) {
            int a = IDX(j + (r << 9));
            v[r] = make_float2(reS[a], imS[a]);
        }
        float ang = (float)DIR * (TWO_PI_F / 2048.0f) * (float)j;
        float2 w1; __sincosf(ang, &w1.y, &w1.x);
        float2 w2 = cmul(w1, w1);
        float2 w3 = cmul(w2, w1);
        v[1] = cmul(v[1], w1);
        v[2] = cmul(v[2], w2);
        v[3] = cmul(v[3], w3);
        fft4v<DIR>(v);
        #pragma unroll
        for (int r = 0; r < 4; ++r) {
            int a = IDX(j + (r << 9));
            reD[a] = v[r].x;
            imD[a] = v[r].y;
        }
    }
}

template <int DIR>
__device__ inline void fft2048(float* reA, float* imA, float* reB, float* imB, int tid) {
    stage8<DIR, 1>(reA, imA, reB, imB, tid);  __syncthreads();
    stage8<DIR, 8>(reB, imB, reA, imA, tid);  __syncthreads();
    stage8<DIR, 64>(reA, imA, reB, imB, tid); __syncthreads();
    stage4_512<DIR>(reB, imB, reA, imA, tid); __syncthreads();
}

// ---------------------------------------------------------------------------
// STFT: one block per frame (696 total). Real-packing + 2048-pt FFT + unpack.
// ---------------------------------------------------------------------------
__global__ __launch_bounds__(256) void stft_kernel(
    const float* __restrict__ x, const float* __restrict__ s,
    float2* __restrict__ Xs, float2* __restrict__ Ss) {
    __shared__ float reA[LDSN], imA[LDSN], reB[LDSN], imB[LDSN];
    int tid = threadIdx.x;
    int fid = blockIdx.x;
    const float* src;
    float2* dst;
    if (fid < NB * NC * NT) {
        int b = fid / (NC * NT);
        int r = fid % (NC * NT);
        int c = r / NT;
        int t = r % NT;
        src = x + (size_t)((b * NC + c) * NS + t * HOP);
        dst = Xs + (size_t)((b * NC + c) * NT + t) * NF;
    } else {
        int g  = fid - NB * NC * NT;
        int bs = g / (NC * NT);
        int r  = g % (NC * NT);
        int c  = r / NT;
        int t  = r % NT;
        src = s + (size_t)((bs * NC + c) * NS + t * HOP);
        dst = Ss + (size_t)((bs * NC + c) * NT + t) * NF;
    }
    const float2* s2 = (const float2*)src;
    for (int n = tid; n < 2048; n += 256) {
        float2 v = s2[n];
        float we = __sinf((float)n * (PI_F / 2048.0f));
        float wo = __sinf((float)(2 * n + 1) * (PI_F / 4096.0f));
        int a = IDX(n);
        reA[a] = v.x * we;
        imA[a] = v.y * wo;
    }
    __syncthreads();
    fft2048<-1>(reA, imA, reB, imB, tid);
    for (int k = tid; k <= 1024; k += 256) {
        int a1 = IDX(k);
        int a2 = IDX((2048 - k) & 2047);
        float2 Za = make_float2(reA[a1], imA[a1]);
        float2 Zb = make_float2(reA[a2], imA[a2]);
        if (k == 0) {
            dst[0]    = make_float2(Za.x + Za.y, 0.f);
            dst[2048] = make_float2(Za.x - Za.y, 0.f);
        } else {
            float2 Ze = make_float2(0.5f * (Za.x + Zb.x),  0.5f * (Za.y - Zb.y));
            float2 Zo = make_float2(0.5f * (Za.y + Zb.y), -0.5f * (Za.x - Zb.x));
            float ang = -(PI_F / 2048.0f) * (float)k;
            float2 W; __sincosf(ang, &W.y, &W.x);
            float2 WZo = cmul(W, Zo);
            dst[k] = make_float2(Ze.x + WZo.x, Ze.y + WZo.y);
            if (k < 1024)
                dst[2048 - k] = make_float2(Ze.x - WZo.x, -(Ze.y - WZo.y));
        }
    }
}

// ---------------------------------------------------------------------------
// Fused MVDR. Block = (bs, 8 f). Coalesced LDS stage-in of (8ch x 32t x 8f);
// compute thread (t,fi): causal PSD via pure-VALU DPP segmented scan (32-lane
// segments, lanes=t); Gauss-Jordan 4x4 Hermitian inverse (reduced column
// range); epilogue via z = ipn^H X, complex trace, e = conj(1/tr) * ps @ z.
// __launch_bounds__(256, 1): ~120+ live floats in the solve; the default
// occupancy heuristic picked 80 VGPRs and spilled ~40 regs to scratch --
// scratch-reload latency inside the serial GJ chain was the 74% stall.
// ---------------------------------------------------------------------------
__global__ __launch_bounds__(256, 1) void mvdr2_kernel(
    const float2* __restrict__ Xs, const float2* __restrict__ Ss,
    float2* __restrict__ Es) {
    __shared__ float2 ldsS[4][32][9];   // also reused as E-staging
    __shared__ float2 ldsX[4][32][9];
    int tid = threadIdx.x;
    int blk = blockIdx.x;
    int bs  = blk / FCHUNKS;
    int f0  = (blk % FCHUNKS) * 8;
    int b   = bs >> 1;

    // ---- coalesced stage-in: 8 q-planes (4 S + 4 X) x 32 t x 8 fi ----
    for (int idx = tid; idx < 2048; idx += 256) {
        int fi = idx & 7;
        int tt = (idx >> 3) & 31;
        int q  = idx >> 8;       // 0..7
        int c  = q & 3;
        int f  = f0 + fi;
        float2 val = make_float2(0.f, 0.f);
        if (tt < NT && f < NF) {
            val = (q >= 4) ? Xs[(size_t)((b  * NC + c) * NT + tt) * NF + f]
                           : Ss[(size_t)((bs * NC + c) * NT + tt) * NF + f];
        }
        if (q >= 4) ldsX[c][tt][fi] = val; else ldsS[c][tt][fi] = val;
    }
    __syncthreads();

    int lane  = tid & 63;
    int wave  = tid >> 6;
    int t     = lane & 31;
    int fpair = lane >> 5;
    int fi    = wave * 2 + fpair;

    float2 Sv[4], Xv[4], Nv[4];
    #pragma unroll
    for (int c = 0; c < 4; ++c) {
        Sv[c] = ldsS[c][t][fi];
        Xv[c] = ldsX[c][t][fi];
        Nv[c] = make_float2(Xv[c].x - Sv[c].x, Xv[c].y - Sv[c].y);
    }

    // 32 scan values: [0..3] ps diag, [4..15] ps off re/im, [16..19] pn diag,
    // [20..31] pn off re/im. Pairs: (0,1),(0,2),(0,3),(1,2),(1,3),(2,3).
    float v[32];
    #pragma unroll
    for (int c = 0; c < 4; ++c) {
        v[c]      = Sv[c].x * Sv[c].x + Sv[c].y * Sv[c].y;
        v[16 + c] = Nv[c].x * Nv[c].x + Nv[c].y * Nv[c].y;
    }
    constexpr int PI6[6] = {0, 0, 0, 1, 1, 2};
    constexpr int PJ6[6] = {1, 2, 3, 2, 3, 3};
    #pragma unroll
    for (int p = 0; p < 6; ++p) {
        float2 d = cmulc(Sv[PI6[p]], Sv[PJ6[p]]);
        v[4 + 2 * p] = d.x; v[5 + 2 * p] = d.y;
        d = cmulc(Nv[PI6[p]], Nv[PJ6[p]]);
        v[20 + 2 * p] = d.x; v[21 + 2 * p] = d.y;
    }

    // Segmented (32-lane) inclusive scan over t, pure VALU via DPP:
    // row_shr 1,2,4,8 within 16-lane rows, then row_bcast15 into odd rows.
    #pragma unroll
    for (int k = 0; k < 32; ++k) v[k] += dpp0<0x111, 0xF>(v[k]);
    #pragma unroll
    for (int k = 0; k < 32; ++k) v[k] += dpp0<0x112, 0xF>(v[k]);
    #pragma unroll
    for (int k = 0; k < 32; ++k) v[k] += dpp0<0x114, 0xF>(v[k]);
    #pragma unroll
    for (int k = 0; k < 32; ++k) v[k] += dpp0<0x118, 0xF>(v[k]);
    #pragma unroll
    for (int k = 0; k < 32; ++k) v[k] += dpp0<0x142, 0xA>(v[k]);

    // Rebuild normalized Hermitian matrices. ps as full 4x4; pn into GJ M.
    float ic = 1.0f / (float)(t + 1);
    float2 ps[4][4];
    float2 M[4][8];
    #pragma unroll
    for (int c = 0; c < 4; ++c) {
        ps[c][c]   = make_float2(v[c] * ic, 0.f);
        M[c][c]    = make_float2(v[16 + c] * ic, 0.f);
        #pragma unroll
        for (int j = 0; j < 4; ++j)
            M[c][4 + j] = make_float2((c == j) ? 1.f : 0.f, 0.f);
    }
    #pragma unroll
    for (int p = 0; p < 6; ++p) {
        int i = PI6[p], j = PJ6[p];
        float re = v[4 + 2 * p] * ic, im = v[5 + 2 * p] * ic;
        ps[i][j] = make_float2(re, im);
        ps[j][i] = make_float2(re, -im);
        re = v[20 + 2 * p] * ic; im = v[21 + 2 * p] * ic;
        M[i][j] = make_float2(re, im);
        M[j][i] = make_float2(re, -im);
    }

    // diagonal loading
    float eps = (M[0][0].x + M[1][1].x + M[2][2].x + M[3][3].x) * 1e-7f + 1e-8f;
    #pragma unroll
    for (int i = 0; i < 4; ++i) M[i][i].x += eps;

    // Gauss-Jordan [pn | I] -> [I | inv(pn)], updating only columns j > col
    // (left half becomes identity; those values are never read again).
    #pragma unroll
    for (int col = 0; col < 4; ++col) {
        float2 piv = M[col][col];
        float  idd = 1.0f / (piv.x * piv.x + piv.y * piv.y);
        float2 pinv = make_float2(piv.x * idd, -piv.y * idd);
        #pragma unroll
        for (int j = col + 1; j < 8; ++j) M[col][j] = cmul(M[col][j], pinv);
        #pragma unroll
        for (int rr = 0; rr < 4; ++rr) {
            if (rr == col) continue;
            float2 fac = M[rr][col];
            #pragma unroll
            for (int j = col + 1; j < 8; ++j) {
                float2 d = cmul(fac, M[col][j]);
                M[rr][j].x -= d.x; M[rr][j].y -= d.y;
            }
        }
    }

    // z_k = sum_a conj(ipn[a][k]) X_a   (ipn[i][k] = M[i][4+k])
    float2 z[4];
    #pragma unroll
    for (int k = 0; k < 4; ++k) {
        float2 acc = make_float2(0.f, 0.f);
        #pragma unroll
        for (int a = 0; a < 4; ++a) {
            float2 q = M[a][4 + k];
            acc.x += q.x * Xv[a].x + q.y * Xv[a].y;
            acc.y += q.x * Xv[a].y - q.y * Xv[a].x;
        }
        z[k] = acc;
    }

    // complex trace tr = 1e-8 + sum_{i,k} ipn[i][k] * ps[k][i]
    float2 trc = make_float2(1e-8f, 0.f);
    #pragma unroll
    for (int i = 0; i < 4; ++i)
        #pragma unroll
        for (int k = 0; k < 4; ++k) {
            float2 q = M[i][4 + k];
            float2 p = ps[k][i];
            trc.x += q.x * p.x - q.y * p.y;
            trc.y += q.x * p.y + q.y * p.x;
        }
    float ginv = 1.0f / (trc.x * trc.x + trc.y * trc.y);
    float2 g = make_float2(trc.x * ginv, trc.y * ginv);  // conj(1/trc)

    // e_bo = g * sum_k ps[bo][k] z_k ; stage into ldsS (own slots only).
    #pragma unroll
    for (int bo = 0; bo < 4; ++bo) {
        float2 u = make_float2(0.f, 0.f);
        #pragma unroll
        for (int k = 0; k < 4; ++k) {
            float2 d = cmul(ps[bo][k], z[k]);
            u.x += d.x; u.y += d.y;
        }
        ldsS[bo][t][fi] = cmul(g, u);
    }
    __syncthreads();

    // ---- coalesced stage-out: 4 bo x 32 t x 8 fi ----
    for (int idx = tid; idx < 1024; idx += 256) {
        int fi2 = idx & 7;
        int tt  = (idx >> 3) & 31;
        int bo  = idx >> 8;
        int ff  = f0 + fi2;
        if (tt < NT && ff < NF)
            Es[(size_t)((bs * NC + bo) * NT + tt) * NF + ff] = ldsS[bo][tt][fi2];
    }
}

// ---------------------------------------------------------------------------
// iSTFT: one block per frame (464). Pack bins, inverse FFT, window, write.
// ---------------------------------------------------------------------------
__global__ __launch_bounds__(256) void istft_kernel(
    const float2* __restrict__ Es, float* __restrict__ Fr) {
    __shared__ float reA[LDSN], imA[LDSN], reB[LDSN], imB[LDSN];
    int tid = threadIdx.x;
    int fid = blockIdx.x;
    int bs = fid / (NC * NT);
    int r  = fid % (NC * NT);
    int c  = r / NT;
    int t  = r % NT;
    const float2* src = Es + (size_t)((bs * NC + c) * NT + t) * NF;
    for (int k = tid; k <= 1024; k += 256) {
        float2 A = src[k];
        float2 B = src[2048 - k];
        float2 Ze = make_float2(0.5f * (A.x + B.x), 0.5f * (A.y - B.y));
        float2 D  = make_float2(0.5f * (A.x - B.x), 0.5f * (A.y + B.y));
        float ang = (PI_F / 2048.0f) * (float)k;
        float2 W; __sincosf(ang, &W.y, &W.x);
        float2 Zo = cmul(W, D);
        int a1 = IDX(k);
        reA[a1] = Ze.x - Zo.y;
        imA[a1] = Ze.y + Zo.x;
        if (k > 0 && k < 1024) {
            int a2 = IDX(2048 - k);
            reA[a2] = Ze.x + Zo.y;
            imA[a2] = -Ze.y + Zo.x;
        }
    }
    __syncthreads();
    fft2048<1>(reA, imA, reB, imB, tid);
    float2* d2 = (float2*)(Fr + (size_t)((bs * NC + c) * NT + t) * NFFT);
    for (int n = tid; n < 2048; n += 256) {
        int a = IDX(n);
        float we = __sinf((float)n * (PI_F / 2048.0f)) * (1.0f / 2048.0f);
        float wo = __sinf((float)(2 * n + 1) * (PI_F / 4096.0f)) * (1.0f / 2048.0f);
        d2[n] = make_float2(reA[a] * we, imA[a] * wo);
    }
}

// ---------------------------------------------------------------------------
// Overlap-add + window-squared normalization. One thread per output sample.
// ---------------------------------------------------------------------------
__global__ __launch_bounds__(256) void ola_kernel(
    const float* __restrict__ Fr, float* __restrict__ out) {
    int idx = blockIdx.x * 256 + threadIdx.x;
    const int total = NBS * NC * NS;
    if (idx >= total) return;
    int p  = idx & (NS - 1);
    int ch = idx >> 15;
    int t1 = p >> 10;
    if (t1 > NT - 1) t1 = NT - 1;
    int t0 = (p >= NFFT) ? ((p - (NFFT - 1) + (HOP - 1)) >> 10) : 0;
    float acc = 0.f, wacc = 0.f;
    for (int t = t0; t <= t1; ++t) {
        int   j = p - (t << 10);
        float w = __sinf((float)j * (PI_F / 4096.0f));
        acc  += Fr[((size_t)(ch * NT + t) << 12) + j];
        wacc += w * w;
    }
    out[idx] = acc / fmaxf(wacc, 1e-8f);
}

// ---------------------------------------------------------------------------
extern "C" void kernel_launch(void* const* d_in, const int* in_sizes, int n_in,
                              void* d_out, int out_size, void* d_ws, size_t ws_size,
                              hipStream_t stream) {
    const float* x = (const float*)d_in[0];  // (2,4,32768)
    const float* s = (const float*)d_in[1];  // (2,2,4,32768)
    float* out = (float*)d_out;              // (2,2,4,32768)

    const size_t XS_N = (size_t)NB  * NC * NT * NF;   // float2
    const size_t SS_N = (size_t)NBS * NC * NT * NF;   // float2
    float2* Xs = (float2*)d_ws;
    float2* Ss = Xs + XS_N;
    float2* Es = Ss + SS_N;
    float*  Fr = (float*)(Es + SS_N);

    stft_kernel<<<NB * NC * NT + NBS * NC * NT, 256, 0, stream>>>(x, s, Xs, Ss);

    mvdr2_kernel<<<NBS * FCHUNKS, 256, 0, stream>>>(Xs, Ss, Es);

    istft_kernel<<<NBS * NC * NT, 256, 0, stream>>>(Es, Fr);

    int ola_total = NBS * NC * NS;   // 524,288
    ola_kernel<<<(ola_total + 255) / 256, 256, 0, stream>>>(Fr, out);
}

// Round 9
// 39.390 us; speedup vs baseline: 1.2603x; 1.1109x over previous
//
#include <hip/hip_runtime.h>

// MVDR beamformer pipeline: STFT -> causal PSD (DPP scan) -> Souden MVDR (LDL^H) -> beamform -> iSTFT
static constexpr int NFFT = 4096;
static constexpr int HOP  = 1024;
static constexpr int NF   = 2049;   // rfft bins
static constexpr int NT   = 29;     // frames
static constexpr int NS   = 32768;  // samples per channel
static constexpr int NB   = 2;      // batch
static constexpr int NSrc = 2;      // sources
static constexpr int NC   = 4;      // channels
static constexpr int NBS  = NB * NSrc;
static constexpr int FCHUNKS = (NF + 7) / 8;  // 257 f-chunks of 8 per block

#define PI_F     3.14159265358979323846f
#define TWO_PI_F 6.28318530717958647692f

// LDS padding: one extra float every 16 -> breaks all power-of-2 stride conflicts
#define IDX(a) ((a) + ((a) >> 4))
static constexpr int LDSN = 2048 + 128;  // padded length

__device__ inline float2 cmul(float2 a, float2 b) {
    return make_float2(a.x * b.x - a.y * b.y, a.x * b.y + a.y * b.x);
}
// a * conj(b)
__device__ inline float2 cmulc(float2 a, float2 b) {
    return make_float2(a.x * b.x + a.y * b.y, a.y * b.x - a.x * b.y);
}

// DPP-shifted source (0 for masked/out-of-range lanes): pure-VALU scan step.
template <int CTRL, int RMASK>
__device__ __forceinline__ float dpp0(float x) {
    return __int_as_float(__builtin_amdgcn_update_dpp(
        0, __float_as_int(x), CTRL, RMASK, 0xF, true));
}

// ---------------------------------------------------------------------------
// 4- and 8-point DFT building blocks. DIR=-1 forward (e^{-i}), +1 inverse.
// ---------------------------------------------------------------------------
template <int DIR>
__device__ inline void fft4v(float2 v[4]) {
    float2 t0 = make_float2(v[0].x + v[2].x, v[0].y + v[2].y);
    float2 t1 = make_float2(v[0].x - v[2].x, v[0].y - v[2].y);
    float2 t2 = make_float2(v[1].x + v[3].x, v[1].y + v[3].y);
    float2 t3 = make_float2(v[1].x - v[3].x, v[1].y - v[3].y);
    v[0] = make_float2(t0.x + t2.x, t0.y + t2.y);
    v[2] = make_float2(t0.x - t2.x, t0.y - t2.y);
    if (DIR < 0) {
        v[1] = make_float2(t1.x + t3.y, t1.y - t3.x);
        v[3] = make_float2(t1.x - t3.y, t1.y + t3.x);
    } else {
        v[1] = make_float2(t1.x - t3.y, t1.y + t3.x);
        v[3] = make_float2(t1.x + t3.y, t1.y - t3.x);
    }
}

template <int DIR>
__device__ inline void fft8v(float2 v[8]) {
    float2 e[4] = { v[0], v[2], v[4], v[6] };
    float2 o[4] = { v[1], v[3], v[5], v[7] };
    fft4v<DIR>(e);
    fft4v<DIR>(o);
    const float c = 0.70710678118654752f;
    float2 o0 = o[0], o1, o2, o3;
    if (DIR < 0) {
        o1 = make_float2(c * (o[1].x + o[1].y), c * (o[1].y - o[1].x));
        o2 = make_float2(o[2].y, -o[2].x);
        o3 = make_float2(c * (o[3].y - o[3].x), -c * (o[3].x + o[3].y));
    } else {
        o1 = make_float2(c * (o[1].x - o[1].y), c * (o[1].y + o[1].x));
        o2 = make_float2(-o[2].y, o[2].x);
        o3 = make_float2(-c * (o[3].x + o[3].y), c * (o[3].x - o[3].y));
    }
    v[0] = make_float2(e[0].x + o0.x, e[0].y + o0.y);
    v[4] = make_float2(e[0].x - o0.x, e[0].y - o0.y);
    v[1] = make_float2(e[1].x + o1.x, e[1].y + o1.y);
    v[5] = make_float2(e[1].x - o1.x, e[1].y - o1.y);
    v[2] = make_float2(e[2].x + o2.x, e[2].y + o2.y);
    v[6] = make_float2(e[2].x - o2.x, e[2].y - o2.y);
    v[3] = make_float2(e[3].x + o3.x, e[3].y + o3.y);
    v[7] = make_float2(e[3].x - o3.x, e[3].y - o3.y);
}

// ---------------------------------------------------------------------------
// Stockham radix-8 stage: src -> dst, 256 threads, one butterfly each.
// ---------------------------------------------------------------------------
template <int DIR, int NSs>
__device__ inline void stage8(const float* __restrict__ reS, const float* __restrict__ imS,
                              float* __restrict__ reD, float* __restrict__ imD, int tid) {
    int j = tid;
    float2 v[8];
    #pragma unroll
    for (int r = 0; r < 8; ++r) {
        int a = IDX(j + (r << 8));
        v[r] = make_float2(reS[a], imS[a]);
    }
    if (NSs > 1) {
        float ang = (float)DIR * (TWO_PI_F / (8.0f * (float)NSs)) * (float)(j & (NSs - 1));
        float2 w1; __sincosf(ang, &w1.y, &w1.x);
        float2 w = w1;
        v[1] = cmul(v[1], w);
        #pragma unroll
        for (int r = 2; r < 8; ++r) { w = cmul(w, w1); v[r] = cmul(v[r], w); }
    }
    fft8v<DIR>(v);
    int idxD = ((j & ~(NSs - 1)) << 3) + (j & (NSs - 1));
    #pragma unroll
    for (int r = 0; r < 8; ++r) {
        int a = IDX(idxD + r * NSs);
        reD[a] = v[r].x;
        imD[a] = v[r].y;
    }
}

// Final radix-4 stage, NS=512: threads handle j = tid and tid+256. Natural order.
template <int DIR>
__device__ inline void stage4_512(const float* __restrict__ reS, const float* __restrict__ imS,
                                  float* __restrict__ reD, float* __restrict__ imD, int tid) {
    #pragma unroll
    for (int h = 0; h < 2; ++h) {
        int j = tid + (h << 8);
        float2 v[4];
        #pragma unroll
        for (int r = 0; r < 4; ++r) {
            int a = IDX(j + (r << 9));
            v[r] = make_float2(reS[a], imS[a]);
        }
        float ang = (float)DIR * (TWO_PI_F / 2048.0f) * (float)j;
        float2 w1; __sincosf(ang, &w1.y, &w1.x);
        float2 w2 = cmul(w1, w1);
        float2 w3 = cmul(w2, w1);
        v[1] = cmul(v[1], w1);
        v[2] = cmul(v[2], w2);
        v[3] = cmul(v[3], w3);
        fft4v<DIR>(v);
        #pragma unroll
        for (int r = 0; r < 4; ++r) {
            int a = IDX(j + (r << 9));
            reD[a] = v[r].x;
            imD[a] = v[r].y;
        }
    }
}

template <int DIR>
__device__ inline void fft2048(float* reA, float* imA, float* reB, float* imB, int tid) {
    stage8<DIR, 1>(reA, imA, reB, imB, tid);  __syncthreads();
    stage8<DIR, 8>(reB, imB, reA, imA, tid);  __syncthreads();
    stage8<DIR, 64>(reA, imA, reB, imB, tid); __syncthreads();
    stage4_512<DIR>(reB, imB, reA, imA, tid); __syncthreads();
}

// ---------------------------------------------------------------------------
// STFT: one block per frame (696 total). Real-packing + 2048-pt FFT + unpack.
// ---------------------------------------------------------------------------
__global__ __launch_bounds__(256) void stft_kernel(
    const float* __restrict__ x, const float* __restrict__ s,
    float2* __restrict__ Xs, float2* __restrict__ Ss) {
    __shared__ float reA[LDSN], imA[LDSN], reB[LDSN], imB[LDSN];
    int tid = threadIdx.x;
    int fid = blockIdx.x;
    const float* src;
    float2* dst;
    if (fid < NB * NC * NT) {
        int b = fid / (NC * NT);
        int r = fid % (NC * NT);
        int c = r / NT;
        int t = r % NT;
        src = x + (size_t)((b * NC + c) * NS + t * HOP);
        dst = Xs + (size_t)((b * NC + c) * NT + t) * NF;
    } else {
        int g  = fid - NB * NC * NT;
        int bs = g / (NC * NT);
        int r  = g % (NC * NT);
        int c  = r / NT;
        int t  = r % NT;
        src = s + (size_t)((bs * NC + c) * NS + t * HOP);
        dst = Ss + (size_t)((bs * NC + c) * NT + t) * NF;
    }
    const float2* s2 = (const float2*)src;
    for (int n = tid; n < 2048; n += 256) {
        float2 v = s2[n];
        float we = __sinf((float)n * (PI_F / 2048.0f));
        float wo = __sinf((float)(2 * n + 1) * (PI_F / 4096.0f));
        int a = IDX(n);
        reA[a] = v.x * we;
        imA[a] = v.y * wo;
    }
    __syncthreads();
    fft2048<-1>(reA, imA, reB, imB, tid);
    for (int k = tid; k <= 1024; k += 256) {
        int a1 = IDX(k);
        int a2 = IDX((2048 - k) & 2047);
        float2 Za = make_float2(reA[a1], imA[a1]);
        float2 Zb = make_float2(reA[a2], imA[a2]);
        if (k == 0) {
            dst[0]    = make_float2(Za.x + Za.y, 0.f);
            dst[2048] = make_float2(Za.x - Za.y, 0.f);
        } else {
            float2 Ze = make_float2(0.5f * (Za.x + Zb.x),  0.5f * (Za.y - Zb.y));
            float2 Zo = make_float2(0.5f * (Za.y + Zb.y), -0.5f * (Za.x - Zb.x));
            float ang = -(PI_F / 2048.0f) * (float)k;
            float2 W; __sincosf(ang, &W.y, &W.x);
            float2 WZo = cmul(W, Zo);
            dst[k] = make_float2(Ze.x + WZo.x, Ze.y + WZo.y);
            if (k < 1024)
                dst[2048 - k] = make_float2(Ze.x - WZo.x, -(Ze.y - WZo.y));
        }
    }
}

// ---------------------------------------------------------------------------
// Fused MVDR. Block = (bs, 8 f). Coalesced LDS stage-in of (8ch x 32t x 8f);
// compute thread (t,fi): causal PSD via pure-VALU DPP segmented scan
// (UNNORMALIZED sums -- ws is invariant to ps,pn scaling; only the diagonal
// load scales: eps = tr(Pn)*1e-7 + (t+1)*1e-8). Then Souden MVDR via LDL^H
// factorization (incremental eliminations, same stability class as GJ):
//   pn = L D L^H;  z = inv(pn) X by fwd/diag/back substitution;
//   tr = sum_i r_i * (K ps K^H)_ii with K = L^-1 (real by construction);
//   e = (1/(tr+1e-8)) * ps @ z.
// All-scalar solve (no arrays -> no dynamic indexing, low VGPR pressure);
// rcp via v_rcp_f32 (1e-7 rel err, well within threshold).
// ---------------------------------------------------------------------------
__global__ __launch_bounds__(256, 1) void mvdr2_kernel(
    const float2* __restrict__ Xs, const float2* __restrict__ Ss,
    float2* __restrict__ Es) {
    __shared__ float2 ldsS[4][32][9];   // also reused as E-staging
    __shared__ float2 ldsX[4][32][9];
    int tid = threadIdx.x;
    int blk = blockIdx.x;
    int bs  = blk / FCHUNKS;
    int f0  = (blk % FCHUNKS) * 8;
    int b   = bs >> 1;

    // ---- coalesced stage-in: 8 q-planes (4 S + 4 X) x 32 t x 8 fi ----
    for (int idx = tid; idx < 2048; idx += 256) {
        int fi = idx & 7;
        int tt = (idx >> 3) & 31;
        int q  = idx >> 8;       // 0..7
        int c  = q & 3;
        int f  = f0 + fi;
        float2 val = make_float2(0.f, 0.f);
        if (tt < NT && f < NF) {
            val = (q >= 4) ? Xs[(size_t)((b  * NC + c) * NT + tt) * NF + f]
                           : Ss[(size_t)((bs * NC + c) * NT + tt) * NF + f];
        }
        if (q >= 4) ldsX[c][tt][fi] = val; else ldsS[c][tt][fi] = val;
    }
    __syncthreads();

    int lane  = tid & 63;
    int wave  = tid >> 6;
    int t     = lane & 31;
    int fpair = lane >> 5;
    int fi    = wave * 2 + fpair;

    float2 Sv[4], Xv[4], Nv[4];
    #pragma unroll
    for (int c = 0; c < 4; ++c) {
        Sv[c] = ldsS[c][t][fi];
        Xv[c] = ldsX[c][t][fi];
        Nv[c] = make_float2(Xv[c].x - Sv[c].x, Xv[c].y - Sv[c].y);
    }

    // 32 scan values: [0..3] ps diag, [4..15] ps off re/im, [16..19] pn diag,
    // [20..31] pn off re/im. Pairs: (0,1),(0,2),(0,3),(1,2),(1,3),(2,3).
    float v[32];
    #pragma unroll
    for (int c = 0; c < 4; ++c) {
        v[c]      = Sv[c].x * Sv[c].x + Sv[c].y * Sv[c].y;
        v[16 + c] = Nv[c].x * Nv[c].x + Nv[c].y * Nv[c].y;
    }
    constexpr int PI6[6] = {0, 0, 0, 1, 1, 2};
    constexpr int PJ6[6] = {1, 2, 3, 2, 3, 3};
    #pragma unroll
    for (int p = 0; p < 6; ++p) {
        float2 d = cmulc(Sv[PI6[p]], Sv[PJ6[p]]);
        v[4 + 2 * p] = d.x; v[5 + 2 * p] = d.y;
        d = cmulc(Nv[PI6[p]], Nv[PJ6[p]]);
        v[20 + 2 * p] = d.x; v[21 + 2 * p] = d.y;
    }

    // Segmented (32-lane) inclusive scan over t, pure VALU via DPP:
    // row_shr 1,2,4,8 within 16-lane rows, then row_bcast15 into odd rows.
    #pragma unroll
    for (int k = 0; k < 32; ++k) v[k] += dpp0<0x111, 0xF>(v[k]);
    #pragma unroll
    for (int k = 0; k < 32; ++k) v[k] += dpp0<0x112, 0xF>(v[k]);
    #pragma unroll
    for (int k = 0; k < 32; ++k) v[k] += dpp0<0x114, 0xF>(v[k]);
    #pragma unroll
    for (int k = 0; k < 32; ++k) v[k] += dpp0<0x118, 0xF>(v[k]);
    #pragma unroll
    for (int k = 0; k < 32; ++k) v[k] += dpp0<0x142, 0xA>(v[k]);

    // Unnormalized Hermitian entries.
    float pd0 = v[0], pd1 = v[1], pd2 = v[2], pd3 = v[3];
    float2 po0 = make_float2(v[4],  v[5]);
    float2 po1 = make_float2(v[6],  v[7]);
    float2 po2 = make_float2(v[8],  v[9]);
    float2 po3 = make_float2(v[10], v[11]);
    float2 po4 = make_float2(v[12], v[13]);
    float2 po5 = make_float2(v[14], v[15]);
    float eps = (v[16] + v[17] + v[18] + v[19]) * 1e-7f + (float)(t + 1) * 1e-8f;
    float nd0 = v[16] + eps, nd1 = v[17] + eps, nd2 = v[18] + eps, nd3 = v[19] + eps;
    float2 no0 = make_float2(v[20], v[21]);
    float2 no1 = make_float2(v[22], v[23]);
    float2 no2 = make_float2(v[24], v[25]);
    float2 no3 = make_float2(v[26], v[27]);
    float2 no4 = make_float2(v[28], v[29]);
    float2 no5 = make_float2(v[30], v[31]);

    // ---- LDL^H: pn = L D L^H (unit-lower L, real D). M[i][j], i>j = conj(no_p).
    float D0 = nd0;
    float r0 = __builtin_amdgcn_rcpf(D0);
    float2 L10 = make_float2(no0.x * r0, -no0.y * r0);
    float2 L20 = make_float2(no1.x * r0, -no1.y * r0);
    float2 L30 = make_float2(no2.x * r0, -no2.y * r0);
    float D1 = nd1 - (L10.x * L10.x + L10.y * L10.y) * D0;
    float r1 = __builtin_amdgcn_rcpf(D1);
    float2 c10 = make_float2(D0 * L10.x, -D0 * L10.y);     // D0*conj(L10)
    float2 tA = cmul(L20, c10);
    float2 L21 = make_float2((no3.x - tA.x) * r1, (-no3.y - tA.y) * r1);
    float2 tB = cmul(L30, c10);
    float2 L31 = make_float2((no4.x - tB.x) * r1, (-no4.y - tB.y) * r1);
    float D2 = nd2 - (L20.x * L20.x + L20.y * L20.y) * D0
                   - (L21.x * L21.x + L21.y * L21.y) * D1;
    float r2 = __builtin_amdgcn_rcpf(D2);
    float2 c20 = make_float2(D0 * L20.x, -D0 * L20.y);
    float2 c21 = make_float2(D1 * L21.x, -D1 * L21.y);
    float2 tC = cmul(L30, c20);
    float2 tD = cmul(L31, c21);
    float2 L32 = make_float2((no5.x - tC.x - tD.x) * r2, (-no5.y - tC.y - tD.y) * r2);
    float D3 = nd3 - (L30.x * L30.x + L30.y * L30.y) * D0
                   - (L31.x * L31.x + L31.y * L31.y) * D1
                   - (L32.x * L32.x + L32.y * L32.y) * D2;
    float r3 = __builtin_amdgcn_rcpf(D3);

    // ---- z = inv(pn) X: forward L u = X, diag, back L^H z = w ----
    float2 u0 = Xv[0];
    float2 m0 = cmul(L10, u0);
    float2 u1 = make_float2(Xv[1].x - m0.x, Xv[1].y - m0.y);
    float2 m1 = cmul(L20, u0), m2 = cmul(L21, u1);
    float2 u2 = make_float2(Xv[2].x - m1.x - m2.x, Xv[2].y - m1.y - m2.y);
    float2 m3 = cmul(L30, u0), m4 = cmul(L31, u1), m5 = cmul(L32, u2);
    float2 u3 = make_float2(Xv[3].x - m3.x - m4.x - m5.x,
                            Xv[3].y - m3.y - m4.y - m5.y);
    float2 w0 = make_float2(u0.x * r0, u0.y * r0);
    float2 w1 = make_float2(u1.x * r1, u1.y * r1);
    float2 w2 = make_float2(u2.x * r2, u2.y * r2);
    float2 w3 = make_float2(u3.x * r3, u3.y * r3);
    float2 z3 = w3;
    float2 n0_ = cmulc(z3, L32);
    float2 z2 = make_float2(w2.x - n0_.x, w2.y - n0_.y);
    float2 n1_ = cmulc(z2, L21), n2_ = cmulc(z3, L31);
    float2 z1 = make_float2(w1.x - n1_.x - n2_.x, w1.y - n1_.y - n2_.y);
    float2 n3_ = cmulc(z1, L10), n4_ = cmulc(z2, L20), n5_ = cmulc(z3, L30);
    float2 z0 = make_float2(w0.x - n3_.x - n4_.x - n5_.x,
                            w0.y - n3_.y - n4_.y - n5_.y);

    // ---- K = L^-1 (unit lower) ----
    float2 K10 = make_float2(-L10.x, -L10.y);
    float2 kk  = cmul(L21, L10);
    float2 K20 = make_float2(kk.x - L20.x, kk.y - L20.y);
    float2 K21 = make_float2(-L21.x, -L21.y);
    kk = cmul(L32, L21);
    float2 K31 = make_float2(kk.x - L31.x, kk.y - L31.y);
    float2 K32 = make_float2(-L32.x, -L32.y);
    float2 ka = cmul(K31, L10), kb = cmul(L32, L20);
    float2 K30 = make_float2(-L30.x - ka.x + kb.x, -L30.y - ka.y + kb.y);

    // ---- tr = sum_i r_i * (K ps K^H)_ii (real quadratic forms) ----
    float q0 = pd0;
    float2 qm = cmul(K10, po0);
    float q1 = pd1 + (K10.x * K10.x + K10.y * K10.y) * pd0 + 2.0f * qm.x;
    qm = cmul(K20, po0);
    float s_a = qm.x * K21.x + qm.y * K21.y;   // Re(K20 po0 conj(K21))
    qm = cmul(K20, po1);
    float s_b = qm.x;
    qm = cmul(K21, po3);
    float s_c = qm.x;
    float q2 = pd2 + (K20.x * K20.x + K20.y * K20.y) * pd0
                   + (K21.x * K21.x + K21.y * K21.y) * pd1
                   + 2.0f * (s_a + s_b + s_c);
    qm = cmul(K30, po0);
    float s1 = qm.x * K31.x + qm.y * K31.y;
    qm = cmul(K30, po1);
    float s2 = qm.x * K32.x + qm.y * K32.y;
    qm = cmul(K30, po2);
    float s3 = qm.x;
    qm = cmul(K31, po3);
    float s4 = qm.x * K32.x + qm.y * K32.y;
    qm = cmul(K31, po4);
    float s5 = qm.x;
    qm = cmul(K32, po5);
    float s6 = qm.x;
    float q3 = pd3 + (K30.x * K30.x + K30.y * K30.y) * pd0
                   + (K31.x * K31.x + K31.y * K31.y) * pd1
                   + (K32.x * K32.x + K32.y * K32.y) * pd2
                   + 2.0f * (s1 + s2 + s3 + s4 + s5 + s6);
    float tr = q0 * r0 + q1 * r1 + q2 * r2 + q3 * r3;
    float g  = __builtin_amdgcn_rcpf(tr + 1e-8f);

    // ---- e = g * ps @ z (Hermitian matvec), stage into ldsS ----
    float2 a0 = cmul(po0, z1), a1 = cmul(po1, z2), a2 = cmul(po2, z3);
    float2 e0 = make_float2(pd0 * z0.x + a0.x + a1.x + a2.x,
                            pd0 * z0.y + a0.y + a1.y + a2.y);
    a0 = cmulc(z0, po0); a1 = cmul(po3, z2); a2 = cmul(po4, z3);
    float2 e1 = make_float2(a0.x + pd1 * z1.x + a1.x + a2.x,
                            a0.y + pd1 * z1.y + a1.y + a2.y);
    a0 = cmulc(z0, po1); a1 = cmulc(z1, po3); a2 = cmul(po5, z3);
    float2 e2 = make_float2(a0.x + a1.x + pd2 * z2.x + a2.x,
                            a0.y + a1.y + pd2 * z2.y + a2.y);
    a0 = cmulc(z0, po2); a1 = cmulc(z1, po4); a2 = cmulc(z2, po5);
    float2 e3 = make_float2(a0.x + a1.x + a2.x + pd3 * z3.x,
                            a0.y + a1.y + a2.y + pd3 * z3.y);
    ldsS[0][t][fi] = make_float2(e0.x * g, e0.y * g);
    ldsS[1][t][fi] = make_float2(e1.x * g, e1.y * g);
    ldsS[2][t][fi] = make_float2(e2.x * g, e2.y * g);
    ldsS[3][t][fi] = make_float2(e3.x * g, e3.y * g);
    __syncthreads();

    // ---- coalesced stage-out: 4 bo x 32 t x 8 fi ----
    for (int idx = tid; idx < 1024; idx += 256) {
        int fi2 = idx & 7;
        int tt  = (idx >> 3) & 31;
        int bo  = idx >> 8;
        int ff  = f0 + fi2;
        if (tt < NT && ff < NF)
            Es[(size_t)((bs * NC + bo) * NT + tt) * NF + ff] = ldsS[bo][tt][fi2];
    }
}

// ---------------------------------------------------------------------------
// iSTFT: one block per frame (464). Pack bins, inverse FFT, window, write.
// ---------------------------------------------------------------------------
__global__ __launch_bounds__(256) void istft_kernel(
    const float2* __restrict__ Es, float* __restrict__ Fr) {
    __shared__ float reA[LDSN], imA[LDSN], reB[LDSN], imB[LDSN];
    int tid = threadIdx.x;
    int fid = blockIdx.x;
    int bs = fid / (NC * NT);
    int r  = fid % (NC * NT);
    int c  = r / NT;
    int t  = r % NT;
    const float2* src = Es + (size_t)((bs * NC + c) * NT + t) * NF;
    for (int k = tid; k <= 1024; k += 256) {
        float2 A = src[k];
        float2 B = src[2048 - k];
        float2 Ze = make_float2(0.5f * (A.x + B.x), 0.5f * (A.y - B.y));
        float2 D  = make_float2(0.5f * (A.x - B.x), 0.5f * (A.y + B.y));
        float ang = (PI_F / 2048.0f) * (float)k;
        float2 W; __sincosf(ang, &W.y, &W.x);
        float2 Zo = cmul(W, D);
        int a1 = IDX(k);
        reA[a1] = Ze.x - Zo.y;
        imA[a1] = Ze.y + Zo.x;
        if (k > 0 && k < 1024) {
            int a2 = IDX(2048 - k);
            reA[a2] = Ze.x + Zo.y;
            imA[a2] = -Ze.y + Zo.x;
        }
    }
    __syncthreads();
    fft2048<1>(reA, imA, reB, imB, tid);
    float2* d2 = (float2*)(Fr + (size_t)((bs * NC + c) * NT + t) * NFFT);
    for (int n = tid; n < 2048; n += 256) {
        int a = IDX(n);
        float we = __sinf((float)n * (PI_F / 2048.0f)) * (1.0f / 2048.0f);
        float wo = __sinf((float)(2 * n + 1) * (PI_F / 4096.0f)) * (1.0f / 2048.0f);
        d2[n] = make_float2(reA[a] * we, imA[a] * wo);
    }
}

// ---------------------------------------------------------------------------
// Overlap-add + window-squared normalization. One thread per output sample.
// ---------------------------------------------------------------------------
__global__ __launch_bounds__(256) void ola_kernel(
    const float* __restrict__ Fr, float* __restrict__ out) {
    int idx = blockIdx.x * 256 + threadIdx.x;
    const int total = NBS * NC * NS;
    if (idx >= total) return;
    int p  = idx & (NS - 1);
    int ch = idx >> 15;
    int t1 = p >> 10;
    if (t1 > NT - 1) t1 = NT - 1;
    int t0 = (p >= NFFT) ? ((p - (NFFT - 1) + (HOP - 1)) >> 10) : 0;
    float acc = 0.f, wacc = 0.f;
    for (int t = t0; t <= t1; ++t) {
        int   j = p - (t << 10);
        float w = __sinf((float)j * (PI_F / 4096.0f));
        acc  += Fr[((size_t)(ch * NT + t) << 12) + j];
        wacc += w * w;
    }
    out[idx] = acc / fmaxf(wacc, 1e-8f);
}

// ---------------------------------------------------------------------------
extern "C" void kernel_launch(void* const* d_in, const int* in_sizes, int n_in,
                              void* d_out, int out_size, void* d_ws, size_t ws_size,
                              hipStream_t stream) {
    const float* x = (const float*)d_in[0];  // (2,4,32768)
    const float* s = (const float*)d_in[1];  // (2,2,4,32768)
    float* out = (float*)d_out;              // (2,2,4,32768)

    const size_t XS_N = (size_t)NB  * NC * NT * NF;   // float2
    const size_t SS_N = (size_t)NBS * NC * NT * NF;   // float2
    float2* Xs = (float2*)d_ws;
    float2* Ss = Xs + XS_N;
    float2* Es = Ss + SS_N;
    float*  Fr = (float*)(Es + SS_N);

    stft_kernel<<<NB * NC * NT + NBS * NC * NT, 256, 0, stream>>>(x, s, Xs, Ss);

    mvdr2_kernel<<<NBS * FCHUNKS, 256, 0, stream>>>(Xs, Ss, Es);

    istft_kernel<<<NBS * NC * NT, 256, 0, stream>>>(Es, Fr);

    int ola_total = NBS * NC * NS;   // 524,288
    ola_kernel<<<(ola_total + 255) / 256, 256, 0, stream>>>(Fr, out);
}